// Round 4
// baseline (245.189 us; speedup 1.0000x reference)
//
#include <hip/hip_runtime.h>
#include <math.h>

#define HH 480
#define WW 640
#define NL 100
#define NREF 20

// ws float layout:
//  [0..239]    tri data: t*12 + e*4 + {ex,ey,vx,vy} for 3 edges
//  [240..259]  FLAGS: 1.0 if rank t < top_num
//  [260..339]  ACC: t*4 + {cnt, sx, sy, sxx+syy}
#define FLAGS_OFF 240
#define ACC_OFF 260

__global__ void plane_setup_kernel(const float* __restrict__ line_pred,
                                   const float* __restrict__ line_score,
                                   float* __restrict__ w) {
    __shared__ float s_sc[NL];
    __shared__ int s_flags[NL];
    __shared__ int s_topnum;
    int i = threadIdx.x; // 0..127

    float s0 = 0.0f;
    if (i < NL) {
        s0 = line_score[2 * i];
        float s1 = line_score[2 * i + 1];
        s_sc[i] = s0;
        float p0 = 1.0f / (1.0f + expf(s1 - s0)); // softmax prob of class 0
        s_flags[i] = (p0 > 0.6f) ? 1 : 0;
    }
    // zero accumulators (ws is re-poisoned to 0xAA every call)
    if (i < NREF * 4) w[ACC_OFF + i] = 0.0f;

    __syncthreads();
    if (i == 0) {
        int nk = 0;
        for (int j = 0; j < NL; j++) nk += s_flags[j];
        s_topnum = (nk < NREF) ? nk : NREF;
    }
    __syncthreads();

    if (i < NL) {
        // stable rank == jax.lax.top_k order (desc, ties -> lower idx); permutation
        int rank = 0;
        for (int j = 0; j < NL; j++) {
            float sj = s_sc[j];
            rank += ((sj > s0) || (sj == s0 && j < i)) ? 1 : 0;
        }
        if (rank < NREF) {
            float c[6];
            #pragma unroll
            for (int q = 0; q < 6; q++) c[q] = line_pred[6 * i + q];
            float vx[3], vy[3];
            #pragma unroll
            for (int v = 0; v < 3; v++) {
                float x = rintf(c[2 * v] * (float)WW);      // round half-even == jnp.round
                float y = rintf(c[2 * v + 1] * (float)HH);
                vx[v] = fminf(fmaxf(x, 0.0f), (float)(WW - 1));
                vy[v] = fminf(fmaxf(y, 0.0f), (float)(HH - 1));
            }
            float* td = w + rank * 12;
            #pragma unroll
            for (int e = 0; e < 3; e++) {
                int n = (e + 1) % 3;
                td[e * 4 + 0] = vx[n] - vx[e]; // ex
                td[e * 4 + 1] = vy[n] - vy[e]; // ey
                td[e * 4 + 2] = vx[e];
                td[e * 4 + 3] = vy[e];
            }
            w[FLAGS_OFF + rank] = (rank < s_topnum) ? 1.0f : 0.0f;
        }
    }
}

// One block per image row. Each wave handles 5 triangles over all 640 px
// (640 = 10*64: no boundary divergence). Gradient computed once per wave.
__global__ __launch_bounds__(256) void plane_main_kernel(
    const float* __restrict__ depth, const int* __restrict__ valid,
    float* __restrict__ w) {
    __shared__ float ds[3 * WW];        // rows r-1, r, r+1 (zero-filled OOB)
    __shared__ int vsh[WW];
    __shared__ float tri8[NREF * 8];    // t*8 + e*2 + {ae, ey}

    const int r = blockIdx.x;
    const int tid = threadIdx.x;
    const float py = (float)r;

    // stage depth: 3 rows x 160 float4
    for (int idx = tid; idx < 3 * (WW / 4); idx += 256) {
        const int lr = idx / (WW / 4);
        const int c4 = idx - lr * (WW / 4);
        const int g = r - 1 + lr;
        float4 v = make_float4(0.f, 0.f, 0.f, 0.f);
        if ((unsigned)g < (unsigned)HH) v = ((const float4*)depth)[g * (WW / 4) + c4];
        ((float4*)ds)[idx] = v;
    }
    // stage valid row
    for (int idx = tid; idx < WW / 4; idx += 256)
        ((int4*)vsh)[idx] = ((const int4*)valid)[r * (WW / 4) + idx];
    // per-row edge constants: d_e(px) = ae_e - ey_e*px  (exact: integer fp32,
    // |terms| < 2^20 -> sign test bitwise-identical to reference's form)
    if (tid < NREF * 3) {
        const int t = tid / 3, e = tid - 3 * t;
        const float* td = w + t * 12 + e * 4;
        const float ex = td[0], ey = td[1], vx = td[2], vy = td[3];
        tri8[t * 8 + e * 2]     = fmaf(ex, py - vy, ey * vx);
        tri8[t * 8 + e * 2 + 1] = ey;
    }
    __syncthreads();

    const int wid = tid >> 6, lane = tid & 63;
    // hoist this wave's 5 triangles' constants (LDS broadcast reads)
    float ae[5][3], ey[5][3];
    #pragma unroll
    for (int i = 0; i < 5; i++)
        #pragma unroll
        for (int e = 0; e < 3; e++) {
            ae[i][e] = tri8[(wid * 5 + i) * 8 + e * 2];
            ey[i][e] = tri8[(wid * 5 + i) * 8 + e * 2 + 1];
        }

    float acc[5][4];
    #pragma unroll
    for (int i = 0; i < 5; i++)
        #pragma unroll
        for (int q = 0; q < 4; q++) acc[i][q] = 0.f;

    #pragma unroll
    for (int j = 0; j < 10; j++) {
        const int x = j * 64 + lane;
        const float px = (float)x;
        const float fl = (x > 0) ? 1.f : 0.f;
        const float fr = (x < WW - 1) ? 1.f : 0.f;
        const int xm = x - (x > 0), xp = x + (x < WW - 1);
        const float a00 = ds[xm] * fl,            a01 = ds[x],            a02 = ds[xp] * fr;
        const float a10 = ds[WW + xm] * fl,                               a12 = ds[WW + xp] * fr;
        const float a20 = ds[2 * WW + xm] * fl,   a21 = ds[2 * WW + x],   a22 = ds[2 * WW + xp] * fr;
        // XLA conv = cross-correlation, zero pad
        const float gx = (a00 - a02) + 2.f * (a10 - a12) + (a20 - a22);
        const float gy = (a00 + 2.f * a01 + a02) - (a20 + 2.f * a21 + a22);
        const float nx = -gx, ny = -gy;
        const float s2 = nx * nx + ny * ny;
        const bool vm = (vsh[x] != 0);
        #pragma unroll
        for (int i = 0; i < 5; i++) {
            const float d0 = fmaf(-ey[i][0], px, ae[i][0]);
            const float d1 = fmaf(-ey[i][1], px, ae[i][1]);
            const float d2 = fmaf(-ey[i][2], px, ae[i][2]);
            const float dmin = fminf(fminf(d0, d1), d2);
            const float dmax = fmaxf(fmaxf(d0, d1), d2);
            const bool m = ((dmin >= 0.f) | (dmax <= 0.f)) & vm;
            const float mf = m ? 1.f : 0.f;
            acc[i][0] += mf;
            acc[i][1] = fmaf(mf, nx, acc[i][1]);
            acc[i][2] = fmaf(mf, ny, acc[i][2]);
            acc[i][3] = fmaf(mf, s2, acc[i][3]);
        }
    }

    // wave-level reduction; waves own disjoint triangles -> no cross-wave step
    #pragma unroll
    for (int off = 32; off > 0; off >>= 1)
        #pragma unroll
        for (int i = 0; i < 5; i++)
            #pragma unroll
            for (int q = 0; q < 4; q++)
                acc[i][q] += __shfl_down(acc[i][q], off);
    if (lane == 0) {
        #pragma unroll
        for (int i = 0; i < 5; i++)
            #pragma unroll
            for (int q = 0; q < 4; q++)
                atomicAdd(&w[ACC_OFF + (wid * 5 + i) * 4 + q], acc[i][q]); // fire-and-forget
    }
}

__global__ void plane_finalize_kernel(const float* __restrict__ w,
                                      float* __restrict__ out) {
    const int tid = threadIdx.x; // 64
    float val = 0.f, inc = 0.f;
    if (tid < NREF) {
        const float* a = w + ACC_OFF + tid * 4;
        const float c = a[0], sx = a[1], sy = a[2], sq = a[3];
        const float safe = fmaxf(c, 1.f);
        const float mx = sx / safe, my = sy / safe;
        // (var_x+var_y) expanded; exact 0 when c==0
        const float var = (sq - 2.f * mx * sx - 2.f * my * sy
                           + c * (mx * mx + my * my)) / safe;
        inc = (c >= 100.f) ? w[FLAGS_OFF + tid] : 0.f;
        val = inc * var;
    }
    #pragma unroll
    for (int off = 32; off > 0; off >>= 1) {
        val += __shfl_down(val, off);
        inc += __shfl_down(inc, off);
    }
    if (tid == 0) out[0] = val / fmaxf(inc, 1.f);
}

extern "C" void kernel_launch(void* const* d_in, const int* in_sizes, int n_in,
                              void* d_out, int out_size, void* d_ws, size_t ws_size,
                              hipStream_t stream) {
    const float* depth_pred = (const float*)d_in[0];
    // d_in[1] = depth_gt (unused by reference)
    const float* line_pred  = (const float*)d_in[2];
    const float* line_score = (const float*)d_in[3];
    const int*   valid_mask = (const int*)d_in[4];
    float* out = (float*)d_out;
    float* w = (float*)d_ws;

    plane_setup_kernel<<<1, 128, 0, stream>>>(line_pred, line_score, w);
    plane_main_kernel<<<HH, 256, 0, stream>>>(depth_pred, valid_mask, w);
    plane_finalize_kernel<<<1, 64, 0, stream>>>(w, out);
}

// Round 5
// 83.570 us; speedup vs baseline: 2.9339x; 2.9339x over previous
//
#include <hip/hip_runtime.h>
#include <math.h>

#define HH 480
#define WW 640
#define NL 100
#define NREF 20

// ws float layout:
//  [0..239]    tri data: t*12 + e*4 + {ex,ey,vx,vy}
//  [240..259]  FLAGS: 1.0 if rank t < top_num
//  [512..]     PART: partial[col][row], col = t*4+q (80 cols), row = 0..479
//              col stride 480 floats (1920 B, 16B-aligned). Total ws ~156 KB.
#define FLAGS_OFF 240
#define PART_OFF 512

__global__ void plane_setup_kernel(const float* __restrict__ line_pred,
                                   const float* __restrict__ line_score,
                                   float* __restrict__ w) {
    __shared__ float s_sc[NL];
    __shared__ int s_flags[NL];
    __shared__ int s_topnum;
    int i = threadIdx.x; // 0..127

    float s0 = 0.0f;
    if (i < NL) {
        s0 = line_score[2 * i];
        float s1 = line_score[2 * i + 1];
        s_sc[i] = s0;
        float p0 = 1.0f / (1.0f + expf(s1 - s0)); // softmax prob of class 0
        s_flags[i] = (p0 > 0.6f) ? 1 : 0;
    }
    __syncthreads();
    if (i == 0) {
        int nk = 0;
        for (int j = 0; j < NL; j++) nk += s_flags[j];
        s_topnum = (nk < NREF) ? nk : NREF;
    }
    __syncthreads();

    if (i < NL) {
        // stable rank == jax.lax.top_k order (desc, ties -> lower idx); permutation
        int rank = 0;
        for (int j = 0; j < NL; j++) {
            float sj = s_sc[j];
            rank += ((sj > s0) || (sj == s0 && j < i)) ? 1 : 0;
        }
        if (rank < NREF) {
            float c[6];
            #pragma unroll
            for (int q = 0; q < 6; q++) c[q] = line_pred[6 * i + q];
            float vx[3], vy[3];
            #pragma unroll
            for (int v = 0; v < 3; v++) {
                float x = rintf(c[2 * v] * (float)WW);      // round half-even == jnp.round
                float y = rintf(c[2 * v + 1] * (float)HH);
                vx[v] = fminf(fmaxf(x, 0.0f), (float)(WW - 1));
                vy[v] = fminf(fmaxf(y, 0.0f), (float)(HH - 1));
            }
            float* td = w + rank * 12;
            #pragma unroll
            for (int e = 0; e < 3; e++) {
                int n = (e + 1) % 3;
                td[e * 4 + 0] = vx[n] - vx[e]; // ex
                td[e * 4 + 1] = vy[n] - vy[e]; // ey
                td[e * 4 + 2] = vx[e];
                td[e * 4 + 3] = vy[e];
            }
            w[FLAGS_OFF + rank] = (rank < s_topnum) ? 1.0f : 0.0f;
        }
    }
}

// One block per image row. Each wave handles 5 triangles over all 640 px
// (640 = 10*64: no boundary divergence). Gradient computed once per wave.
// NO atomics: each wave plain-stores 20 partials to its private ws slice.
__global__ __launch_bounds__(256) void plane_main_kernel(
    const float* __restrict__ depth, const int* __restrict__ valid,
    float* __restrict__ w) {
    __shared__ float ds[3 * WW];        // rows r-1, r, r+1 (zero-filled OOB)
    __shared__ int vsh[WW];
    __shared__ float tri8[NREF * 8];    // t*8 + e*2 + {ae, ey}

    const int r = blockIdx.x;
    const int tid = threadIdx.x;
    const float py = (float)r;

    // stage depth: 3 rows x 160 float4
    for (int idx = tid; idx < 3 * (WW / 4); idx += 256) {
        const int lr = idx / (WW / 4);
        const int c4 = idx - lr * (WW / 4);
        const int g = r - 1 + lr;
        float4 v = make_float4(0.f, 0.f, 0.f, 0.f);
        if ((unsigned)g < (unsigned)HH) v = ((const float4*)depth)[g * (WW / 4) + c4];
        ((float4*)ds)[idx] = v;
    }
    // stage valid row
    for (int idx = tid; idx < WW / 4; idx += 256)
        ((int4*)vsh)[idx] = ((const int4*)valid)[r * (WW / 4) + idx];
    // per-row edge constants: d_e(px) = ae_e - ey_e*px  (exact: integer fp32
    // operands, |terms| < 2^21 -> sign test bitwise-identical to reference)
    if (tid < NREF * 3) {
        const int t = tid / 3, e = tid - 3 * t;
        const float* td = w + t * 12 + e * 4;
        const float ex = td[0], eyv = td[1], vx = td[2], vy = td[3];
        tri8[t * 8 + e * 2]     = fmaf(ex, py - vy, eyv * vx);
        tri8[t * 8 + e * 2 + 1] = eyv;
    }
    __syncthreads();

    const int wid = tid >> 6, lane = tid & 63;
    // hoist this wave's 5 triangles' constants (LDS broadcast reads)
    float ae[5][3], ey[5][3];
    #pragma unroll
    for (int i = 0; i < 5; i++)
        #pragma unroll
        for (int e = 0; e < 3; e++) {
            ae[i][e] = tri8[(wid * 5 + i) * 8 + e * 2];
            ey[i][e] = tri8[(wid * 5 + i) * 8 + e * 2 + 1];
        }

    float acc[5][4];
    #pragma unroll
    for (int i = 0; i < 5; i++)
        #pragma unroll
        for (int q = 0; q < 4; q++) acc[i][q] = 0.f;

    #pragma unroll
    for (int j = 0; j < 10; j++) {
        const int x = j * 64 + lane;
        const float px = (float)x;
        const float fl = (x > 0) ? 1.f : 0.f;
        const float fr = (x < WW - 1) ? 1.f : 0.f;
        const int xm = x - (x > 0), xp = x + (x < WW - 1);
        const float a00 = ds[xm] * fl,          a01 = ds[x],          a02 = ds[xp] * fr;
        const float a10 = ds[WW + xm] * fl,                           a12 = ds[WW + xp] * fr;
        const float a20 = ds[2 * WW + xm] * fl, a21 = ds[2 * WW + x], a22 = ds[2 * WW + xp] * fr;
        // XLA conv = cross-correlation, zero pad
        const float gx = (a00 - a02) + 2.f * (a10 - a12) + (a20 - a22);
        const float gy = (a00 + 2.f * a01 + a02) - (a20 + 2.f * a21 + a22);
        const float nx = -gx, ny = -gy;
        const float s2 = nx * nx + ny * ny;
        const bool vm = (vsh[x] != 0);
        #pragma unroll
        for (int i = 0; i < 5; i++) {
            const float d0 = fmaf(-ey[i][0], px, ae[i][0]);
            const float d1 = fmaf(-ey[i][1], px, ae[i][1]);
            const float d2 = fmaf(-ey[i][2], px, ae[i][2]);
            const float dmin = fminf(fminf(d0, d1), d2);
            const float dmax = fmaxf(fmaxf(d0, d1), d2);
            const bool m = ((dmin >= 0.f) | (dmax <= 0.f)) & vm;
            const float mf = m ? 1.f : 0.f;
            acc[i][0] += mf;
            acc[i][1] = fmaf(mf, nx, acc[i][1]);
            acc[i][2] = fmaf(mf, ny, acc[i][2]);
            acc[i][3] = fmaf(mf, s2, acc[i][3]);
        }
    }

    // wave-level reduction; waves own disjoint triangles -> no cross-wave step
    #pragma unroll
    for (int off = 32; off > 0; off >>= 1)
        #pragma unroll
        for (int i = 0; i < 5; i++)
            #pragma unroll
            for (int q = 0; q < 4; q++)
                acc[i][q] += __shfl_down(acc[i][q], off);
    if (lane == 0) {
        // plain stores, zero contention: col = (wid*5+i)*4+q, row = r
        #pragma unroll
        for (int i = 0; i < 5; i++)
            #pragma unroll
            for (int q = 0; q < 4; q++)
                w[PART_OFF + ((wid * 5 + i) * 4 + q) * HH + r] = acc[i][q];
    }
}

__global__ __launch_bounds__(128) void plane_finalize_kernel(
    const float* __restrict__ w, float* __restrict__ out) {
    __shared__ float s_col[NREF * 4];
    const int tid = threadIdx.x; // 0..127
    // stage 1: 80 threads sum their column (480 contiguous floats, float4)
    if (tid < NREF * 4) {
        const float4* col = (const float4*)(w + PART_OFF + tid * HH);
        float4 s4 = make_float4(0.f, 0.f, 0.f, 0.f);
        #pragma unroll 8
        for (int p = 0; p < HH / 4; p++) {
            float4 v = col[p];
            s4.x += v.x; s4.y += v.y; s4.z += v.z; s4.w += v.w;
        }
        s_col[tid] = (s4.x + s4.y) + (s4.z + s4.w);
    }
    __syncthreads();
    // stage 2: per-triangle variance + masked mean over included triangles
    float val = 0.f, inc = 0.f;
    if (tid < NREF) {
        const float c  = s_col[tid * 4 + 0];
        const float sx = s_col[tid * 4 + 1];
        const float sy = s_col[tid * 4 + 2];
        const float sq = s_col[tid * 4 + 3];
        const float safe = fmaxf(c, 1.f);
        const float mx = sx / safe, my = sy / safe;
        // (var_x+var_y) expanded; exact 0 when c==0
        const float var = (sq - 2.f * mx * sx - 2.f * my * sy
                           + c * (mx * mx + my * my)) / safe;
        inc = (c >= 100.f) ? w[FLAGS_OFF + tid] : 0.f;
        val = inc * var;
    }
    if (tid < 64) { // lanes 20..63 carry zeros
        #pragma unroll
        for (int off = 32; off > 0; off >>= 1) {
            val += __shfl_down(val, off);
            inc += __shfl_down(inc, off);
        }
        if (tid == 0) out[0] = val / fmaxf(inc, 1.f);
    }
}

extern "C" void kernel_launch(void* const* d_in, const int* in_sizes, int n_in,
                              void* d_out, int out_size, void* d_ws, size_t ws_size,
                              hipStream_t stream) {
    const float* depth_pred = (const float*)d_in[0];
    // d_in[1] = depth_gt (unused by reference)
    const float* line_pred  = (const float*)d_in[2];
    const float* line_score = (const float*)d_in[3];
    const int*   valid_mask = (const int*)d_in[4];
    float* out = (float*)d_out;
    float* w = (float*)d_ws;

    plane_setup_kernel<<<1, 128, 0, stream>>>(line_pred, line_score, w);
    plane_main_kernel<<<HH, 256, 0, stream>>>(depth_pred, valid_mask, w);
    plane_finalize_kernel<<<1, 128, 0, stream>>>(w, out);
}

// Round 6
// 79.077 us; speedup vs baseline: 3.1007x; 1.0568x over previous
//
#include <hip/hip_runtime.h>
#include <math.h>

#define HH 480
#define WW 640
#define NL 100
#define NREF 20
#define RPB 2                 /* rows per block */
#define NB (HH / RPB)         /* 240 blocks */

// ws layout: PART only. partial[col][block], col = t*4+q (80 cols),
// col stride NB floats (960 B, 16B-aligned). ~76.8 KB. No zeroing needed:
// every entry is plain-stored by its owning block (no atomics anywhere).

// One block per 2 image rows. Block derives its own triangle set from
// line_score/line_pred in LDS (overlapped, removes the setup kernel + its
// serial latency). Each wave handles 5 triangles over all 640 px
// (640 = 10*64: no boundary divergence). Gradient computed once per wave.
__global__ __launch_bounds__(256) void plane_main_kernel(
    const float* __restrict__ depth, const int* __restrict__ valid,
    const float* __restrict__ line_pred, const float* __restrict__ line_score,
    float* __restrict__ w) {
    __shared__ float ds[(RPB + 2) * WW];   // rows base-1 .. base+RPB (zero-filled OOB)
    __shared__ int vsh[RPB * WW];
    __shared__ float s_sc[NL];
    __shared__ float s_vert[NREF][6];      // vx,vy x 3 per rank
    __shared__ float s_ae[RPB][NREF * 3];  // per-row edge constant
    __shared__ float s_ey[NREF * 3];

    const int tid = threadIdx.x;
    const int base = blockIdx.x * RPB;

    if (tid < NL) s_sc[tid] = ((const float2*)line_score)[tid].x;

    // stage depth: (RPB+2) rows x 160 float4
    for (int idx = tid; idx < (RPB + 2) * (WW / 4); idx += 256) {
        const int lr = idx / (WW / 4);
        const int c4 = idx - lr * (WW / 4);
        const int g = base - 1 + lr;
        float4 v = make_float4(0.f, 0.f, 0.f, 0.f);
        if ((unsigned)g < (unsigned)HH) v = ((const float4*)depth)[g * (WW / 4) + c4];
        ((float4*)ds)[idx] = v;
    }
    // stage valid rows
    for (int idx = tid; idx < RPB * (WW / 4); idx += 256)
        ((int4*)vsh)[idx] = ((const int4*)valid)[base * (WW / 4) + idx];
    __syncthreads();

    // stable rank == jax.lax.top_k order (desc, ties -> lower idx); permutation
    if (tid < NL) {
        const float s0 = s_sc[tid];
        int rank = 0;
        for (int j = 0; j < NL; j++) {
            const float sj = s_sc[j];
            rank += ((sj > s0) || (sj == s0 && j < tid)) ? 1 : 0;
        }
        if (rank < NREF) {
            const float2 c01 = ((const float2*)line_pred)[3 * tid];
            const float2 c23 = ((const float2*)line_pred)[3 * tid + 1];
            const float2 c45 = ((const float2*)line_pred)[3 * tid + 2];
            // round half-even == jnp.round; clip to image
            s_vert[rank][0] = fminf(fmaxf(rintf(c01.x * (float)WW), 0.f), (float)(WW - 1));
            s_vert[rank][1] = fminf(fmaxf(rintf(c01.y * (float)HH), 0.f), (float)(HH - 1));
            s_vert[rank][2] = fminf(fmaxf(rintf(c23.x * (float)WW), 0.f), (float)(WW - 1));
            s_vert[rank][3] = fminf(fmaxf(rintf(c23.y * (float)HH), 0.f), (float)(HH - 1));
            s_vert[rank][4] = fminf(fmaxf(rintf(c45.x * (float)WW), 0.f), (float)(WW - 1));
            s_vert[rank][5] = fminf(fmaxf(rintf(c45.y * (float)HH), 0.f), (float)(HH - 1));
        }
    }
    __syncthreads();

    // per-row edge constants: d_e(px) = ae_e - ey_e*px (exact: integer fp32
    // operands, |terms| < 2^22 -> sign test bitwise-identical to reference)
    if (tid < NREF * 3) {
        const int t = tid / 3, e = tid - 3 * t, n = (e + 1) % 3;
        const float vx = s_vert[t][2 * e], vy = s_vert[t][2 * e + 1];
        const float ex = s_vert[t][2 * n] - vx, eyv = s_vert[t][2 * n + 1] - vy;
        s_ey[tid] = eyv;
        #pragma unroll
        for (int rr = 0; rr < RPB; rr++)
            s_ae[rr][tid] = fmaf(ex, (float)(base + rr) - vy, eyv * vx);
    }
    __syncthreads();

    const int wid = tid >> 6, lane = tid & 63;
    float eyr[5][3];
    #pragma unroll
    for (int i = 0; i < 5; i++)
        #pragma unroll
        for (int e = 0; e < 3; e++)
            eyr[i][e] = s_ey[(wid * 5 + i) * 3 + e];

    float acc[5][4];
    #pragma unroll
    for (int i = 0; i < 5; i++)
        #pragma unroll
        for (int q = 0; q < 4; q++) acc[i][q] = 0.f;

    #pragma unroll
    for (int rr = 0; rr < RPB; rr++) {
        float ae[5][3];
        #pragma unroll
        for (int i = 0; i < 5; i++)
            #pragma unroll
            for (int e = 0; e < 3; e++)
                ae[i][e] = s_ae[rr][(wid * 5 + i) * 3 + e];
        const float* rm = ds + rr * WW;
        const float* rc = ds + (rr + 1) * WW;
        const float* rp = ds + (rr + 2) * WW;
        const int* vrow = vsh + rr * WW;
        #pragma unroll
        for (int j = 0; j < 10; j++) {
            const int x = j * 64 + lane;
            const float px = (float)x;
            const float fl = (x > 0) ? 1.f : 0.f;
            const float fr = (x < WW - 1) ? 1.f : 0.f;
            const int xm = x - (x > 0), xp = x + (x < WW - 1);
            const float a00 = rm[xm] * fl, a01 = rm[x], a02 = rm[xp] * fr;
            const float a10 = rc[xm] * fl,               a12 = rc[xp] * fr;
            const float a20 = rp[xm] * fl, a21 = rp[x], a22 = rp[xp] * fr;
            // XLA conv = cross-correlation, zero pad
            const float gx = (a00 - a02) + 2.f * (a10 - a12) + (a20 - a22);
            const float gy = (a00 + 2.f * a01 + a02) - (a20 + 2.f * a21 + a22);
            const float nx = -gx, ny = -gy;
            const float s2 = nx * nx + ny * ny;
            const bool vm = (vrow[x] != 0);
            #pragma unroll
            for (int i = 0; i < 5; i++) {
                const float d0 = fmaf(-eyr[i][0], px, ae[i][0]);
                const float d1 = fmaf(-eyr[i][1], px, ae[i][1]);
                const float d2 = fmaf(-eyr[i][2], px, ae[i][2]);
                const float dmin = fminf(fminf(d0, d1), d2);
                const float dmax = fmaxf(fmaxf(d0, d1), d2);
                const bool m = ((dmin >= 0.f) | (dmax <= 0.f)) & vm;
                const float mf = m ? 1.f : 0.f;
                acc[i][0] += mf;
                acc[i][1] = fmaf(mf, nx, acc[i][1]);
                acc[i][2] = fmaf(mf, ny, acc[i][2]);
                acc[i][3] = fmaf(mf, s2, acc[i][3]);
            }
        }
    }

    // wave-level reduction; waves own disjoint triangles -> no cross-wave step
    #pragma unroll
    for (int off = 32; off > 0; off >>= 1)
        #pragma unroll
        for (int i = 0; i < 5; i++)
            #pragma unroll
            for (int q = 0; q < 4; q++)
                acc[i][q] += __shfl_down(acc[i][q], off);
    if (lane == 0) {
        // plain stores, zero contention: col = (wid*5+i)*4+q, row = blockIdx.x
        #pragma unroll
        for (int i = 0; i < 5; i++)
            #pragma unroll
            for (int q = 0; q < 4; q++)
                w[((wid * 5 + i) * 4 + q) * NB + blockIdx.x] = acc[i][q];
    }
}

__global__ __launch_bounds__(128) void plane_finalize_kernel(
    const float* __restrict__ line_score, const float* __restrict__ w,
    float* __restrict__ out) {
    __shared__ float s_col[NREF * 4];
    __shared__ int s_cnt[2];
    const int tid = threadIdx.x; // 0..127
    const int lane = tid & 63, wid = tid >> 6;

    // top_num = min(#(softmax prob0 > 0.6), 20); include-flag = (rank < top_num)
    int flag = 0;
    if (tid < NL) {
        const float2 sc = ((const float2*)line_score)[tid];
        const float p0 = 1.0f / (1.0f + expf(sc.y - sc.x));
        flag = (p0 > 0.6f) ? 1 : 0;
    }
    const unsigned long long b = __ballot(flag);
    if (lane == 0) s_cnt[wid] = __popcll(b);

    // sum partial columns (NB contiguous floats each, float4)
    if (tid < NREF * 4) {
        const float4* col = (const float4*)(w + tid * NB);
        float4 s4 = make_float4(0.f, 0.f, 0.f, 0.f);
        #pragma unroll 4
        for (int p = 0; p < NB / 4; p++) {
            const float4 v = col[p];
            s4.x += v.x; s4.y += v.y; s4.z += v.z; s4.w += v.w;
        }
        s_col[tid] = (s4.x + s4.y) + (s4.z + s4.w);
    }
    __syncthreads();

    const int topnum = min(s_cnt[0] + s_cnt[1], NREF);
    float val = 0.f, inc = 0.f;
    if (tid < NREF) {
        const float c  = s_col[tid * 4 + 0];
        const float sx = s_col[tid * 4 + 1];
        const float sy = s_col[tid * 4 + 2];
        const float sq = s_col[tid * 4 + 3];
        const float safe = fmaxf(c, 1.f);
        const float mx = sx / safe, my = sy / safe;
        // (var_x+var_y) expanded; exact 0 when c==0
        const float var = (sq - 2.f * mx * sx - 2.f * my * sy
                           + c * (mx * mx + my * my)) / safe;
        inc = ((c >= 100.f) && (tid < topnum)) ? 1.f : 0.f;
        val = inc * var;
    }
    if (tid < 64) { // lanes 20..63 carry zeros
        #pragma unroll
        for (int off = 32; off > 0; off >>= 1) {
            val += __shfl_down(val, off);
            inc += __shfl_down(inc, off);
        }
        if (tid == 0) out[0] = val / fmaxf(inc, 1.f);
    }
}

extern "C" void kernel_launch(void* const* d_in, const int* in_sizes, int n_in,
                              void* d_out, int out_size, void* d_ws, size_t ws_size,
                              hipStream_t stream) {
    const float* depth_pred = (const float*)d_in[0];
    // d_in[1] = depth_gt (unused by reference)
    const float* line_pred  = (const float*)d_in[2];
    const float* line_score = (const float*)d_in[3];
    const int*   valid_mask = (const int*)d_in[4];
    float* out = (float*)d_out;
    float* w = (float*)d_ws;

    plane_main_kernel<<<NB, 256, 0, stream>>>(depth_pred, valid_mask,
                                              line_pred, line_score, w);
    plane_finalize_kernel<<<1, 128, 0, stream>>>(line_score, w, out);
}